// Round 7
// baseline (207.092 us; speedup 1.0000x reference)
//
#include <hip/hip_runtime.h>
#include <hip/hip_bf16.h>
#include <type_traits>

#define N_ROWS 20000
#define KNBR   32
#define M_ROWS 100000
#define INF    256
#define DIMW   64

#define GRID_J ((M_ROWS + 63) / 64)   // 1563
#define GRID_V ((N_ROWS + 63) / 64)   // 313

typedef __attribute__((ext_vector_type(8))) short short8v;
typedef __attribute__((ext_vector_type(4))) float f32x4;
typedef __attribute__((ext_vector_type(2))) float f32x2;
typedef __attribute__((ext_vector_type(2))) unsigned u32x2;

// bf16 bits -> float (exact)
__device__ __forceinline__ float bfu(unsigned short s) {
    return __uint_as_float((unsigned)s << 16);
}
// f32 -> bf16 bits (RN)
__device__ __forceinline__ unsigned short f2b(float x) {
    union { __hip_bfloat16 h; unsigned short u; } cv;
    cv.h = __float2bfloat16(x);
    return cv.u;
}
__device__ __forceinline__ unsigned pk2(float a, float b) {
    return (unsigned)f2b(a) | ((unsigned)f2b(b) << 16);
}

// ---------------------------------------------------------------------------
// Prep: transpose+convert weights to bf16 [col][k] layout; zero table row 0;
// pack v -> vh (64 u32 of bf16 pairs).
// ---------------------------------------------------------------------------
__global__ void prep_wt(const float* __restrict__ W2, const float* __restrict__ W1w,
                        const float* __restrict__ W1v, const float* __restrict__ v,
                        unsigned short* __restrict__ WtJ, unsigned short* __restrict__ WtW,
                        unsigned short* __restrict__ WtV, unsigned* __restrict__ vh,
                        unsigned short* __restrict__ tabJ, unsigned short* __restrict__ tabW)
{
    int idx = blockIdx.x * 256 + threadIdx.x;
    if (idx < 128 * 256) {
        int c = idx >> 8, k = idx & 255;
        WtJ[idx] = f2b(W2[k * 128 + c]);
    } else if (idx < 128 * 256 + 128 * 64) {
        int i2 = idx - 128 * 256;
        int c = i2 >> 6, k = i2 & 63;
        WtW[i2] = f2b(W1w[k * 128 + c]);
    } else if (idx < 2 * 128 * 256 + 128 * 64) {
        int i3 = idx - (128 * 256 + 128 * 64);
        int c = i3 >> 8, k = i3 & 255;
        WtV[i3] = f2b(W1v[k * 128 + c]);
    }
    if (idx < 128) { tabJ[idx] = 0; tabW[idx] = 0; }
    if (idx < 64)  { vh[idx] = pk2(v[2 * idx], v[2 * idx + 1]); }
}

// ---------------------------------------------------------------------------
// GEMM body (device fn): out[(r+rowOffset)][0..127] = bf16(A[r][:]) @ W (+bias)
// Tile 64 rows x 128 cols, BK=64; 4 waves in 2x2 (each 32 rows x 64 cols).
// C/D layout: col = l&15, row = (l>>4)*4 + reg  [learn_hip m89].
// ---------------------------------------------------------------------------
template <int F, bool WRITE_AH, bool BIAS>
__device__ __forceinline__ void gemm_body(
    const float* __restrict__ A, const unsigned short* __restrict__ Wt,
    unsigned short* __restrict__ outB, unsigned short* __restrict__ Ah,
    const float* __restrict__ bias, int R, int rowOffset, int m0,
    unsigned short* __restrict__ As,    // [64][64] swizzled bf16
    unsigned short* __restrict__ Ws,    // [128][64] swizzled bf16
    unsigned short* __restrict__ Tile)  // [64][136] bf16
{
    const int t   = threadIdx.x;
    const int wid = t >> 6;
    const int l   = t & 63;
    const int l15 = l & 15;
    const int l4  = l >> 4;
    const int wr  = wid >> 1;          // 0..1: row half
    const int wc  = wid & 1;           // 0..1: col half

    f32x4 acc[2][4];
    #pragma unroll
    for (int rg = 0; rg < 2; rg++)
        #pragma unroll
        for (int ct = 0; ct < 4; ct++) acc[rg][ct] = (f32x4){0.f, 0.f, 0.f, 0.f};

    const int ar  = t >> 2;            // A row 0..63
    const int ac  = (t & 3) * 16;      // 16 f32 per thread
    const int wrS = t >> 1;            // Wt row (W col) 0..127
    const int wcS = (t & 1) * 32;      // 32 bf16 per thread

    for (int k0 = 0; k0 < F; k0 += 64) {
        // ---- stage A (f32 -> bf16), fused Ah write ----
        {
            int r = m0 + ar;
            unsigned pk[8];
            if (r < R) {
                const float* ap = A + (size_t)r * F + k0 + ac;
                #pragma unroll
                for (int q = 0; q < 4; q++) {
                    f32x4 f = *(const f32x4*)(ap + q * 4);
                    pk[q * 2 + 0] = pk2(f.x, f.y);
                    pk[q * 2 + 1] = pk2(f.z, f.w);
                }
                if (WRITE_AH) {
                    uint4 lo = {pk[0], pk[1], pk[2], pk[3]};
                    uint4 hi = {pk[4], pk[5], pk[6], pk[7]};
                    *(uint4*)(Ah + (size_t)r * F + k0 + ac)     = lo;
                    *(uint4*)(Ah + (size_t)r * F + k0 + ac + 8) = hi;
                }
            } else {
                #pragma unroll
                for (int q = 0; q < 8; q++) pk[q] = 0u;
            }
            int base = ar * 128 + ac * 2;       // bytes
            int swz  = (ar & 7) << 4;
            uint4 lo = {pk[0], pk[1], pk[2], pk[3]};
            uint4 hi = {pk[4], pk[5], pk[6], pk[7]};
            *(uint4*)((char*)As + ((base)      ^ swz)) = lo;
            *(uint4*)((char*)As + ((base + 16) ^ swz)) = hi;
        }
        // ---- stage Wt ----
        {
            const unsigned short* wp = Wt + (size_t)wrS * F + k0 + wcS;
            int base = wrS * 128 + wcS * 2;
            int swz  = (wrS & 7) << 4;
            #pragma unroll
            for (int q = 0; q < 4; q++) {
                uint4 wv = *(const uint4*)(wp + q * 8);
                *(uint4*)((char*)Ws + ((base + q * 16) ^ swz)) = wv;
            }
        }
        __syncthreads();

        // ---- MFMA ----
        short8v afrag[2][2];
        #pragma unroll
        for (int rg = 0; rg < 2; rg++) {
            int arow = wr * 32 + rg * 16 + l15;
            int aswz = (arow & 7) << 4;
            #pragma unroll
            for (int ks = 0; ks < 2; ks++) {
                int boff = arow * 128 + (ks * 32 + l4 * 8) * 2;
                afrag[rg][ks] = *(const short8v*)((const char*)As + (boff ^ aswz));
            }
        }
        #pragma unroll
        for (int ct = 0; ct < 4; ct++) {
            int bcol = wc * 64 + ct * 16 + l15;
            int bswz = (bcol & 7) << 4;
            #pragma unroll
            for (int ks = 0; ks < 2; ks++) {
                int boff = bcol * 128 + (ks * 32 + l4 * 8) * 2;
                short8v bfrag = *(const short8v*)((const char*)Ws + (boff ^ bswz));
                #pragma unroll
                for (int rg = 0; rg < 2; rg++)
                    acc[rg][ct] = __builtin_amdgcn_mfma_f32_16x16x32_bf16(afrag[rg][ks], bfrag, acc[rg][ct], 0, 0, 0);
            }
        }
        __syncthreads();
    }

    // ---- repack through LDS (+bias), coalesced bf16 store ----
    #pragma unroll
    for (int rg = 0; rg < 2; rg++)
        #pragma unroll
        for (int ct = 0; ct < 4; ct++) {
            int col = wc * 64 + ct * 16 + l15;
            float bb = BIAS ? bias[col] : 0.f;
            #pragma unroll
            for (int i = 0; i < 4; i++)
                Tile[(wr * 32 + rg * 16 + l4 * 4 + i) * 136 + col] = f2b(acc[rg][ct][i] + bb);
        }
    __syncthreads();
    {
        int row = t >> 2, part = t & 3;
        int gr = m0 + row;
        if (gr < R) {
            unsigned short* op = outB + (size_t)(gr + rowOffset) * 128 + part * 32;
            const unsigned short* tp = Tile + row * 136 + part * 32;
            #pragma unroll
            for (int q = 0; q < 4; q++)
                *(uint4*)(op + q * 8) = *(const uint4*)(tp + q * 8);
        }
    }
    __syncthreads();
}

// ---------------------------------------------------------------------------
// One fused kernel for all three table GEMMs.
// ---------------------------------------------------------------------------
__global__ __launch_bounds__(256) void tables_fused(
    const float* __restrict__ ej, const float* __restrict__ ew,
    const float* __restrict__ ev,
    const unsigned short* __restrict__ WtJ, const unsigned short* __restrict__ WtW,
    const unsigned short* __restrict__ WtV,
    unsigned short* __restrict__ tabJ, unsigned short* __restrict__ tabW,
    unsigned short* __restrict__ evW1, unsigned short* __restrict__ ejh,
    const float* __restrict__ bias)
{
    __shared__ __align__(16) unsigned short As[64 * 64];
    __shared__ __align__(16) unsigned short Ws[128 * 64];
    __shared__ __align__(16) unsigned short Tile[64 * 136];

    const int bid = blockIdx.x;
    if (bid < GRID_J) {
        const int m0 = bid * 64;
        gemm_body<INF,  true,  false>(ej, WtJ, tabJ, ejh,     nullptr, M_ROWS, 1, m0, As, Ws, Tile);
        gemm_body<DIMW, false, false>(ew, WtW, tabW, nullptr, nullptr, M_ROWS, 1, m0, As, Ws, Tile);
    } else {
        const int m0 = (bid - GRID_J) * 64;
        gemm_body<INF,  false, true >(ev, WtV, evW1, nullptr, bias,    N_ROWS, 0, m0, As, Ws, Tile);
    }
}

// ---------------------------------------------------------------------------
// Wave-per-n fused score + softmax + weighted gather.
// 4 waves per block, one n each. No LDS, no barriers.
// Lane l: k = l>>1, h = l&1 (64-channel half). All cross-lane via shuffles.
// ---------------------------------------------------------------------------
__global__ __launch_bounds__(256) void score_out(
    const unsigned short* __restrict__ tabJ, const unsigned short* __restrict__ tabW,
    const unsigned short* __restrict__ evW1, const unsigned short* __restrict__ ejh,
    const int* __restrict__ vj, const int* __restrict__ vw,
    const unsigned* __restrict__ vh, float* __restrict__ out)
{
    const int wave = threadIdx.x >> 6;
    const int l    = threadIdx.x & 63;
    const int n    = blockIdx.x * 4 + wave;

    // ---- indices: lanes 0..31 hold j_k, lanes 32..63 hold w_k ----
    int jv = 0, wv = 0;
    if (l < 32) jv = vj[n * KNBR + l];
    else        wv = vw[n * KNBR + (l - 32)];

    const int k = l >> 1;
    const int h = l & 1;
    const int jk = __shfl(jv, k);
    const int wk = __shfl(wv, 32 + k);

    // ---- score: 64 channels [h*64, h*64+64) for neighbor k ----
    const uint4* tj4 = (const uint4*)(tabJ + (size_t)jk * 128 + h * 64);
    const uint4* tw4 = (const uint4*)(tabW + (size_t)wk * 128 + h * 64);
    const uint4* ev4 = (const uint4*)(evW1 + (size_t)n * 128 + h * 64);
    const uint4* vv4 = (const uint4*)(vh + h * 32);

    float x = 0.f;
    #pragma unroll
    for (int q = 0; q < 8; q++) {
        uint4 J = tj4[q], W = tw4[q], E = ev4[q], V = vv4[q];
        unsigned ja[4] = {J.x, J.y, J.z, J.w};
        unsigned wa[4] = {W.x, W.y, W.z, W.w};
        unsigned ea[4] = {E.x, E.y, E.z, E.w};
        unsigned va[4] = {V.x, V.y, V.z, V.w};
        #pragma unroll
        for (int p = 0; p < 4; p++) {
            float av0 = bfu((unsigned short)(ea[p] & 0xffff))
                      + bfu((unsigned short)(ja[p] & 0xffff))
                      + bfu((unsigned short)(wa[p] & 0xffff));
            float av1 = bfu((unsigned short)(ea[p] >> 16))
                      + bfu((unsigned short)(ja[p] >> 16))
                      + bfu((unsigned short)(wa[p] >> 16));
            x = fmaf(fmaxf(av0, 0.f), bfu((unsigned short)(va[p] & 0xffff)), x);
            x = fmaf(fmaxf(av1, 0.f), bfu((unsigned short)(va[p] >> 16)),    x);
        }
    }
    x += __shfl_xor(x, 1);               // lanes 2k,2k+1 now hold x_k

    // ---- softmax over 32 k (values duplicated pairwise across 64 lanes).
    // Butterfly over xor-bits 1..5 reaches exactly ONE lane per (2k,2k+1)
    // pair -> s = sum over the 32 distinct x_k (each once), mx = true max.
    float mx = x;
    #pragma unroll
    for (int m = 2; m <= 32; m <<= 1) mx = fmaxf(mx, __shfl_xor(mx, m));
    float e = __expf(x - mx);
    float s = e;
    #pragma unroll
    for (int m = 2; m <= 32; m <<= 1) s += __shfl_xor(s, m);
    const float a = e / s;                // lane holds a_k for k = l>>1

    // ---- weighted gather: lane owns features [4l, 4l+4) ----
    float a0 = 0.f, a1 = 0.f, a2 = 0.f, a3 = 0.f;
    #pragma unroll
    for (int k2 = 0; k2 < KNBR; k2++) {
        int   j2 = __shfl(jv, k2);
        float ak = __shfl(a, k2 * 2);
        int   jm = (j2 > 0) ? (j2 - 1) : 0;          // clamped row, always load
        float m2 = (j2 > 0) ? ak : 0.f;              // mask kills pad contribution
        u32x2 u  = *(const u32x2*)(ejh + (size_t)jm * 256 + l * 4);
        a0 = fmaf(m2, bfu((unsigned short)(u.x & 0xffff)), a0);
        a1 = fmaf(m2, bfu((unsigned short)(u.x >> 16)),    a1);
        a2 = fmaf(m2, bfu((unsigned short)(u.y & 0xffff)), a2);
        a3 = fmaf(m2, bfu((unsigned short)(u.y >> 16)),    a3);
    }
    f32x4 r = {a0, a1, a2, a3};
    __builtin_nontemporal_store(r, (f32x4*)(out + (size_t)n * 256 + l * 4));
}

// ---------------------------------------------------------------------------
extern "C" void kernel_launch(void* const* d_in, const int* in_sizes, int n_in,
                              void* d_out, int out_size, void* d_ws, size_t ws_size,
                              hipStream_t stream)
{
    const float* ev = (const float*)d_in[0];
    const float* ej = (const float*)d_in[1];
    const float* ew = (const float*)d_in[2];
    const int*   vj = (const int*)d_in[3];
    const int*   vw = (const int*)d_in[4];
    const float* W1 = (const float*)d_in[5];   // [320][128]
    const float* W2 = (const float*)d_in[6];   // [256][128]
    const float* b  = (const float*)d_in[7];   // [128]
    const float* v  = (const float*)d_in[8];   // [128]
    float* out = (float*)d_out;

    const float* W1v = W1;                     // rows 0..255
    const float* W1w = W1 + 256 * 128;         // rows 256..319

    // workspace layout (bf16), ~107.8 MB
    unsigned short* tabJ = (unsigned short*)d_ws;                      // (M+1)*128
    unsigned short* tabW = tabJ + (size_t)(M_ROWS + 1) * 128;          // (M+1)*128
    unsigned short* ejh  = tabW + (size_t)(M_ROWS + 1) * 128;          // M*256
    unsigned short* evW1 = ejh  + (size_t)M_ROWS * 256;                // N*128
    unsigned short* WtJ  = evW1 + (size_t)N_ROWS * 128;                // 128*256
    unsigned short* WtW  = WtJ  + 128 * 256;                           // 128*64
    unsigned short* WtV  = WtW  + 128 * 64;                            // 128*256
    unsigned*       vh   = (unsigned*)(WtV + 128 * 256);               // 64 u32

    prep_wt<<<288, 256, 0, stream>>>(W2, W1w, W1v, v, WtJ, WtW, WtV, vh, tabJ, tabW);
    tables_fused<<<GRID_J + GRID_V, 256, 0, stream>>>(ej, ew, ev, WtJ, WtW, WtV,
                                                      tabJ, tabW, evW1, ejh, b);
    score_out<<<(N_ROWS + 3) / 4, 256, 0, stream>>>(tabJ, tabW, evW1, ejh, vj, vw, vh, out);
}

// Round 8
// 148.931 us; speedup vs baseline: 1.3905x; 1.3905x over previous
//
#include <hip/hip_runtime.h>
#include <hip/hip_bf16.h>
#include <type_traits>

#define N_ROWS 20000
#define KNBR   32
#define M_ROWS 100000
#define INF    256
#define DIMW   64

#define GRID_J ((M_ROWS + 63) / 64)   // 1563
#define GRID_V ((N_ROWS + 63) / 64)   // 313

typedef __attribute__((ext_vector_type(8))) short short8v;
typedef __attribute__((ext_vector_type(4))) float f32x4;
typedef __attribute__((ext_vector_type(2))) float f32x2;

// bf16 bits -> float (exact)
__device__ __forceinline__ float bfu(unsigned short s) {
    return __uint_as_float((unsigned)s << 16);
}
// f32 -> bf16 bits (RN)
__device__ __forceinline__ unsigned short f2b(float x) {
    union { __hip_bfloat16 h; unsigned short u; } cv;
    cv.h = __float2bfloat16(x);
    return cv.u;
}
__device__ __forceinline__ unsigned pk2(float a, float b) {
    return (unsigned)f2b(a) | ((unsigned)f2b(b) << 16);
}

// ---------------------------------------------------------------------------
// Prep: transpose+convert weights to bf16 [col][k] layout; zero table row 0.
// ---------------------------------------------------------------------------
__global__ void prep_wt(const float* __restrict__ W2, const float* __restrict__ W1w,
                        const float* __restrict__ W1v,
                        unsigned short* __restrict__ WtJ, unsigned short* __restrict__ WtW,
                        unsigned short* __restrict__ WtV,
                        unsigned short* __restrict__ tabJ, unsigned short* __restrict__ tabW)
{
    int idx = blockIdx.x * 256 + threadIdx.x;
    if (idx < 128 * 256) {
        int c = idx >> 8, k = idx & 255;
        WtJ[idx] = f2b(W2[k * 128 + c]);
    } else if (idx < 128 * 256 + 128 * 64) {
        int i2 = idx - 128 * 256;
        int c = i2 >> 6, k = i2 & 63;
        WtW[i2] = f2b(W1w[k * 128 + c]);
    } else if (idx < 2 * 128 * 256 + 128 * 64) {
        int i3 = idx - (128 * 256 + 128 * 64);
        int c = i3 >> 8, k = i3 & 255;
        WtV[i3] = f2b(W1v[k * 128 + c]);
    }
    if (idx < 128) { tabJ[idx] = 0; tabW[idx] = 0; }
}

// ---------------------------------------------------------------------------
// GEMM body (device fn): out[(r+rowOffset)][0..127] = bf16(A[r][:]) @ W (+bias)
// Tile 64 rows x 128 cols, BK=64; 4 waves in 2x2 (each 32 rows x 64 cols).
// C/D layout: col = l&15, row = (l>>4)*4 + reg  [learn_hip m89].
// ---------------------------------------------------------------------------
template <int F, bool WRITE_AH, bool BIAS>
__device__ __forceinline__ void gemm_body(
    const float* __restrict__ A, const unsigned short* __restrict__ Wt,
    unsigned short* __restrict__ outB, unsigned short* __restrict__ Ah,
    const float* __restrict__ bias, int R, int rowOffset, int m0,
    unsigned short* __restrict__ As,    // [64][64] swizzled bf16
    unsigned short* __restrict__ Ws,    // [128][64] swizzled bf16
    unsigned short* __restrict__ Tile)  // [64][136] bf16
{
    const int t   = threadIdx.x;
    const int wid = t >> 6;
    const int l   = t & 63;
    const int l15 = l & 15;
    const int l4  = l >> 4;
    const int wr  = wid >> 1;          // 0..1: row half
    const int wc  = wid & 1;           // 0..1: col half

    f32x4 acc[2][4];
    #pragma unroll
    for (int rg = 0; rg < 2; rg++)
        #pragma unroll
        for (int ct = 0; ct < 4; ct++) acc[rg][ct] = (f32x4){0.f, 0.f, 0.f, 0.f};

    const int ar  = t >> 2;            // A row 0..63
    const int ac  = (t & 3) * 16;      // 16 f32 per thread
    const int wrS = t >> 1;            // Wt row (W col) 0..127
    const int wcS = (t & 1) * 32;      // 32 bf16 per thread

    for (int k0 = 0; k0 < F; k0 += 64) {
        // ---- stage A (f32 -> bf16), fused Ah write ----
        {
            int r = m0 + ar;
            unsigned pk[8];
            if (r < R) {
                const float* ap = A + (size_t)r * F + k0 + ac;
                #pragma unroll
                for (int q = 0; q < 4; q++) {
                    f32x4 f = *(const f32x4*)(ap + q * 4);
                    pk[q * 2 + 0] = pk2(f.x, f.y);
                    pk[q * 2 + 1] = pk2(f.z, f.w);
                }
                if (WRITE_AH) {
                    uint4 lo = {pk[0], pk[1], pk[2], pk[3]};
                    uint4 hi = {pk[4], pk[5], pk[6], pk[7]};
                    *(uint4*)(Ah + (size_t)r * F + k0 + ac)     = lo;
                    *(uint4*)(Ah + (size_t)r * F + k0 + ac + 8) = hi;
                }
            } else {
                #pragma unroll
                for (int q = 0; q < 8; q++) pk[q] = 0u;
            }
            int base = ar * 128 + ac * 2;       // bytes
            int swz  = (ar & 7) << 4;
            uint4 lo = {pk[0], pk[1], pk[2], pk[3]};
            uint4 hi = {pk[4], pk[5], pk[6], pk[7]};
            *(uint4*)((char*)As + ((base)      ^ swz)) = lo;
            *(uint4*)((char*)As + ((base + 16) ^ swz)) = hi;
        }
        // ---- stage Wt ----
        {
            const unsigned short* wp = Wt + (size_t)wrS * F + k0 + wcS;
            int base = wrS * 128 + wcS * 2;
            int swz  = (wrS & 7) << 4;
            #pragma unroll
            for (int q = 0; q < 4; q++) {
                uint4 wv = *(const uint4*)(wp + q * 8);
                *(uint4*)((char*)Ws + ((base + q * 16) ^ swz)) = wv;
            }
        }
        __syncthreads();

        // ---- MFMA ----
        short8v afrag[2][2];
        #pragma unroll
        for (int rg = 0; rg < 2; rg++) {
            int arow = wr * 32 + rg * 16 + l15;
            int aswz = (arow & 7) << 4;
            #pragma unroll
            for (int ks = 0; ks < 2; ks++) {
                int boff = arow * 128 + (ks * 32 + l4 * 8) * 2;
                afrag[rg][ks] = *(const short8v*)((const char*)As + (boff ^ aswz));
            }
        }
        #pragma unroll
        for (int ct = 0; ct < 4; ct++) {
            int bcol = wc * 64 + ct * 16 + l15;
            int bswz = (bcol & 7) << 4;
            #pragma unroll
            for (int ks = 0; ks < 2; ks++) {
                int boff = bcol * 128 + (ks * 32 + l4 * 8) * 2;
                short8v bfrag = *(const short8v*)((const char*)Ws + (boff ^ bswz));
                #pragma unroll
                for (int rg = 0; rg < 2; rg++)
                    acc[rg][ct] = __builtin_amdgcn_mfma_f32_16x16x32_bf16(afrag[rg][ks], bfrag, acc[rg][ct], 0, 0, 0);
            }
        }
        __syncthreads();
    }

    // ---- repack through LDS (+bias), coalesced bf16 store ----
    #pragma unroll
    for (int rg = 0; rg < 2; rg++)
        #pragma unroll
        for (int ct = 0; ct < 4; ct++) {
            int col = wc * 64 + ct * 16 + l15;
            float bb = BIAS ? bias[col] : 0.f;
            #pragma unroll
            for (int i = 0; i < 4; i++)
                Tile[(wr * 32 + rg * 16 + l4 * 4 + i) * 136 + col] = f2b(acc[rg][ct][i] + bb);
        }
    __syncthreads();
    {
        int row = t >> 2, part = t & 3;
        int gr = m0 + row;
        if (gr < R) {
            unsigned short* op = outB + (size_t)(gr + rowOffset) * 128 + part * 32;
            const unsigned short* tp = Tile + row * 136 + part * 32;
            #pragma unroll
            for (int q = 0; q < 4; q++)
                *(uint4*)(op + q * 8) = *(const uint4*)(tp + q * 8);
        }
    }
    __syncthreads();
}

// ---------------------------------------------------------------------------
// One fused kernel for all three table GEMMs.
// ---------------------------------------------------------------------------
__global__ __launch_bounds__(256) void tables_fused(
    const float* __restrict__ ej, const float* __restrict__ ew,
    const float* __restrict__ ev,
    const unsigned short* __restrict__ WtJ, const unsigned short* __restrict__ WtW,
    const unsigned short* __restrict__ WtV,
    unsigned short* __restrict__ tabJ, unsigned short* __restrict__ tabW,
    unsigned short* __restrict__ evW1, unsigned short* __restrict__ ejh,
    const float* __restrict__ bias)
{
    __shared__ __align__(16) unsigned short As[64 * 64];
    __shared__ __align__(16) unsigned short Ws[128 * 64];
    __shared__ __align__(16) unsigned short Tile[64 * 136];

    const int bid = blockIdx.x;
    if (bid < GRID_J) {
        const int m0 = bid * 64;
        gemm_body<INF,  true,  false>(ej, WtJ, tabJ, ejh,     nullptr, M_ROWS, 1, m0, As, Ws, Tile);
        gemm_body<DIMW, false, false>(ew, WtW, tabW, nullptr, nullptr, M_ROWS, 1, m0, As, Ws, Tile);
    } else {
        const int m0 = (bid - GRID_J) * 64;
        gemm_body<INF,  false, true >(ev, WtV, evW1, nullptr, bias,    N_ROWS, 0, m0, As, Ws, Tile);
    }
}

// ---------------------------------------------------------------------------
// Fused score + softmax + weighted gather, block-per-2n (Round-4 structure,
// doubled in-flight misses per thread).
// ---------------------------------------------------------------------------
__global__ __launch_bounds__(256) void score_out(
    const unsigned short* __restrict__ tabJ, const unsigned short* __restrict__ tabW,
    const unsigned short* __restrict__ evW1, const unsigned short* __restrict__ ejh,
    const int* __restrict__ vj, const int* __restrict__ vw,
    const float* __restrict__ vvec, float* __restrict__ out)
{
    const int n0 = blockIdx.x * 2;
    const int t  = threadIdx.x;

    __shared__ float  s_ev[2][128];
    __shared__ float  s_v[128];
    __shared__ int    s_j[2][32];
    __shared__ int    s_w[2][32];
    __shared__ float  s_a[2][32];
    __shared__ float2 s_red[2][2][128];

    if (t < 128) {
        s_ev[0][t] = bfu(evW1[(size_t)n0 * 128 + t]);
        s_ev[1][t] = bfu(evW1[(size_t)(n0 + 1) * 128 + t]);
        s_v[t]     = vvec[t];
    } else if (t < 192) {
        int q  = t - 128;          // 0..63
        int ni = q >> 5, kk = q & 31;
        s_j[ni][kk] = vj[(n0 + ni) * KNBR + kk];
        s_w[ni][kk] = vw[(n0 + ni) * KNBR + kk];
    }
    __syncthreads();

    // ---- scores: thread t -> neighbor k = t>>3, cols [cg*16, cg*16+16) ----
    const int k  = t >> 3;
    const int cg = t & 7;

    // issue all 8 row loads (2 n x {tabJ,tabW} x 2 uint4) before computing
    uint4 J[2][2], W[2][2];
    #pragma unroll
    for (int ni = 0; ni < 2; ni++) {
        const uint4* tj4 = (const uint4*)(tabJ + (size_t)s_j[ni][k] * 128 + cg * 16);
        const uint4* tw4 = (const uint4*)(tabW + (size_t)s_w[ni][k] * 128 + cg * 16);
        J[ni][0] = tj4[0]; J[ni][1] = tj4[1];
        W[ni][0] = tw4[0]; W[ni][1] = tw4[1];
    }
    #pragma unroll
    for (int ni = 0; ni < 2; ni++) {
        unsigned jw[8] = {J[ni][0].x, J[ni][0].y, J[ni][0].z, J[ni][0].w,
                          J[ni][1].x, J[ni][1].y, J[ni][1].z, J[ni][1].w};
        unsigned ww[8] = {W[ni][0].x, W[ni][0].y, W[ni][0].z, W[ni][0].w,
                          W[ni][1].x, W[ni][1].y, W[ni][1].z, W[ni][1].w};
        float x = 0.f;
        #pragma unroll
        for (int p = 0; p < 8; p++) {
            int c0 = cg * 16 + p * 2;
            float av0 = s_ev[ni][c0]     + bfu((unsigned short)(jw[p] & 0xffff))
                                         + bfu((unsigned short)(ww[p] & 0xffff));
            float av1 = s_ev[ni][c0 + 1] + bfu((unsigned short)(jw[p] >> 16))
                                         + bfu((unsigned short)(ww[p] >> 16));
            x = fmaf(fmaxf(av0, 0.f), s_v[c0], x);
            x = fmaf(fmaxf(av1, 0.f), s_v[c0 + 1], x);
        }
        x += __shfl_xor(x, 1);
        x += __shfl_xor(x, 2);
        x += __shfl_xor(x, 4);
        if (cg == 0) s_a[ni][k] = x;
    }
    __syncthreads();

    // ---- softmax over K=32, two n in the two halves of wave 0 ----
    if (t < 64) {
        int ni = t >> 5, tt = t & 31;
        float xi = s_a[ni][tt];
        float mx = xi;
        #pragma unroll
        for (int m = 16; m >= 1; m >>= 1) mx = fmaxf(mx, __shfl_xor(mx, m));
        float e = __expf(xi - mx);
        float s = e;
        #pragma unroll
        for (int m = 16; m >= 1; m >>= 1) s += __shfl_xor(s, m);
        s_a[ni][tt] = e / s;
    }
    __syncthreads();

    // ---- weighted gather: thread owns feature pair p, k-half h, both n ----
    const int p = t & 127;
    const int h = t >> 7;
    unsigned uu[2][16];
    float    aa[2][16];
    #pragma unroll
    for (int ni = 0; ni < 2; ni++)
        #pragma unroll
        for (int kk = 0; kk < 16; kk++) {      // issue all 32 loads first
            int k2 = h * 16 + kk;
            int j2 = s_j[ni][k2];
            aa[ni][kk] = s_a[ni][k2];
            uu[ni][kk] = j2 ? *(const unsigned*)(ejh + (size_t)(j2 - 1) * 256 + p * 2) : 0u;
        }
    #pragma unroll
    for (int ni = 0; ni < 2; ni++) {
        float2 accv = {0.f, 0.f};
        #pragma unroll
        for (int kk = 0; kk < 16; kk++) {
            accv.x = fmaf(aa[ni][kk], bfu((unsigned short)(uu[ni][kk] & 0xffff)), accv.x);
            accv.y = fmaf(aa[ni][kk], bfu((unsigned short)(uu[ni][kk] >> 16)),    accv.y);
        }
        s_red[ni][h][p] = accv;
    }
    __syncthreads();
    {
        int ni = t >> 7, f = t & 127;
        float2 a0 = s_red[ni][0][f], a1 = s_red[ni][1][f];
        f32x2 r = {a0.x + a1.x, a0.y + a1.y};
        __builtin_nontemporal_store(r, (f32x2*)(out + (size_t)(n0 + ni) * 256 + f * 2));
    }
}

// ---------------------------------------------------------------------------
extern "C" void kernel_launch(void* const* d_in, const int* in_sizes, int n_in,
                              void* d_out, int out_size, void* d_ws, size_t ws_size,
                              hipStream_t stream)
{
    const float* ev = (const float*)d_in[0];
    const float* ej = (const float*)d_in[1];
    const float* ew = (const float*)d_in[2];
    const int*   vj = (const int*)d_in[3];
    const int*   vw = (const int*)d_in[4];
    const float* W1 = (const float*)d_in[5];   // [320][128]
    const float* W2 = (const float*)d_in[6];   // [256][128]
    const float* b  = (const float*)d_in[7];   // [128]
    const float* v  = (const float*)d_in[8];   // [128]
    float* out = (float*)d_out;

    const float* W1v = W1;                     // rows 0..255
    const float* W1w = W1 + 256 * 128;         // rows 256..319

    // workspace layout (bf16), ~107.8 MB
    unsigned short* tabJ = (unsigned short*)d_ws;                      // (M+1)*128
    unsigned short* tabW = tabJ + (size_t)(M_ROWS + 1) * 128;          // (M+1)*128
    unsigned short* ejh  = tabW + (size_t)(M_ROWS + 1) * 128;          // M*256
    unsigned short* evW1 = ejh  + (size_t)M_ROWS * 256;                // N*128
    unsigned short* WtJ  = evW1 + (size_t)N_ROWS * 128;                // 128*256
    unsigned short* WtW  = WtJ  + 128 * 256;                           // 128*64
    unsigned short* WtV  = WtW  + 128 * 64;                            // 128*256

    prep_wt<<<288, 256, 0, stream>>>(W2, W1w, W1v, WtJ, WtW, WtV, tabJ, tabW);
    tables_fused<<<GRID_J + GRID_V, 256, 0, stream>>>(ej, ew, ev, WtJ, WtW, WtV,
                                                      tabJ, tabW, evW1, ejh, b);
    score_out<<<N_ROWS / 2, 256, 0, stream>>>(tabJ, tabW, evW1, ejh, vj, vw, v, out);
}